// Round 1
// baseline (1879.101 us; speedup 1.0000x reference)
//
#include <hip/hip_runtime.h>
#include <stdint.h>

#define E4M3_MAX 448.0f

typedef float f32x4 __attribute__((ext_vector_type(4)));

// ---------------------------------------------------------------------------
// async global -> LDS, 16 bytes per lane (global_load_lds_dwordx4)
// LDS dest must be wave-uniform base + lane*16 (HW constraint).
// ---------------------------------------------------------------------------
__device__ __forceinline__ void gload_lds16(const void* g, void* l) {
    __builtin_amdgcn_global_load_lds(
        (__attribute__((address_space(1))) void*)(void*)g,
        (__attribute__((address_space(3))) void*)l,
        16, 0, 0);
}

// pack 4 floats -> 4 e4m3fn bytes (RNE + saturate; pre-clamp matches jnp.clip)
__device__ __forceinline__ uint32_t quant4(float a, float b, float c, float d) {
    a = fminf(fmaxf(a, -E4M3_MAX), E4M3_MAX);
    b = fminf(fmaxf(b, -E4M3_MAX), E4M3_MAX);
    c = fminf(fmaxf(c, -E4M3_MAX), E4M3_MAX);
    d = fminf(fmaxf(d, -E4M3_MAX), E4M3_MAX);
    int q = 0;
    q = __builtin_amdgcn_cvt_pk_fp8_f32(a, b, q, false);  // bytes 0,1
    q = __builtin_amdgcn_cvt_pk_fp8_f32(c, d, q, true);   // bytes 2,3
    return (uint32_t)q;
}

// ---------------------------------------------------------------------------
// quantize x: [M*K] f32 -> e4m3 bytes, scale = 1/in_scale (scalar)
// 16 elements / thread / iter, float4 loads, uint4 stores.
// ---------------------------------------------------------------------------
__global__ void quant_x_kernel(const float* __restrict__ x,
                               const float* __restrict__ scale_p,
                               uint4* __restrict__ xq, int n16) {
    const float inv = 1.0f / scale_p[0];
    const int stride = gridDim.x * blockDim.x;
    for (int i = blockIdx.x * blockDim.x + threadIdx.x; i < n16; i += stride) {
        const float4* p = (const float4*)x + (size_t)i * 4;
        float4 v0 = p[0], v1 = p[1], v2 = p[2], v3 = p[3];
        uint4 q;
        q.x = quant4(v0.x * inv, v0.y * inv, v0.z * inv, v0.w * inv);
        q.y = quant4(v1.x * inv, v1.y * inv, v1.z * inv, v1.w * inv);
        q.z = quant4(v2.x * inv, v2.y * inv, v2.z * inv, v2.w * inv);
        q.w = quant4(v3.x * inv, v3.y * inv, v3.z * inv, v3.w * inv);
        xq[i] = q;
    }
}

// ---------------------------------------------------------------------------
// quantize w: [N*K] f32 -> e4m3 bytes, per-chunk scale w_scales[c]
// chunk16 = number of 16-elem groups per chunk.
// ---------------------------------------------------------------------------
__global__ void quant_w_kernel(const float* __restrict__ w,
                               const float* __restrict__ wsc,
                               uint4* __restrict__ wq, int n16, int chunk16) {
    const int stride = gridDim.x * blockDim.x;
    for (int i = blockIdx.x * blockDim.x + threadIdx.x; i < n16; i += stride) {
        const float inv = 1.0f / wsc[i / chunk16];
        const float4* p = (const float4*)w + (size_t)i * 4;
        float4 v0 = p[0], v1 = p[1], v2 = p[2], v3 = p[3];
        uint4 q;
        q.x = quant4(v0.x * inv, v0.y * inv, v0.z * inv, v0.w * inv);
        q.y = quant4(v1.x * inv, v1.y * inv, v1.z * inv, v1.w * inv);
        q.z = quant4(v2.x * inv, v2.y * inv, v2.z * inv, v2.w * inv);
        q.w = quant4(v3.x * inv, v3.y * inv, v3.z * inv, v3.w * inv);
        wq[i] = q;
    }
}

// ---------------------------------------------------------------------------
// fp8 GEMM, m97 structure: 128x128 tile, BK=128 (bytes), 4 waves (2x2),
// each wave 64x64 = 4x4 fragments of 16x16, mfma_f32_16x16x32_fp8_fp8.
// A = xq [M][K] row-major, B = wq [N][K] row-major (both K-contiguous).
// Epilogue: out = acc * (in_scale * w_scales[n / ocPerChunk]) + bias[n].
// ---------------------------------------------------------------------------
#define BM 128
#define BN 128
#define BKB 128  // K-bytes per LDS tile

__global__ __launch_bounds__(256, 3) void gemm_fp8_kernel(
    const uint8_t* __restrict__ Aq, const uint8_t* __restrict__ Bq,
    const float* __restrict__ bias, const float* __restrict__ isp,
    const float* __restrict__ wsc, float* __restrict__ out,
    int M, int N, int K, int ocPerChunk) {
    __shared__ __align__(16) uint8_t As[BM * BKB];
    __shared__ __align__(16) uint8_t Bs[BN * BKB];

    const int tid  = threadIdx.x;
    const int lane = tid & 63;
    const int wid  = tid >> 6;
    const int wm   = wid >> 1;   // 0..1
    const int wn   = wid & 1;    // 0..1
    const int m0   = blockIdx.y * BM;
    const int n0   = blockIdx.x * BN;

    const int lr = lane & 15;          // fragment row (A) / col (B)
    const int lk = (lane >> 4) * 8;    // k byte offset within 32-wide k-step

    f32x4 acc[4][4] = {};

    const uint8_t* pa = As + (wm * 64 + lr) * BKB + lk;
    const uint8_t* pb = Bs + (wn * 64 + lr) * BKB + lk;

    for (int kt = 0; kt < K; kt += BKB) {
        // ---- stage A,B tiles (8 x global_load_lds_dwordx4 per thread) ----
#pragma unroll
        for (int i = 0; i < 4; i++) {
            int idx = i * 256 + tid;          // 0..1023
            int row = idx >> 3;               // 0..127
            int cb  = (idx & 7) * 16;         // byte col within BKB
            gload_lds16(Aq + (size_t)(m0 + row) * K + kt + cb, As + idx * 16);
            gload_lds16(Bq + (size_t)(n0 + row) * K + kt + cb, Bs + idx * 16);
        }
        __syncthreads();  // compiler emits vmcnt(0) drain before barrier

        // ---- 4 k-steps of 32, 16 MFMA each ----
#pragma unroll
        for (int kk = 0; kk < BKB; kk += 32) {
            long av[4], bv[4];
#pragma unroll
            for (int t = 0; t < 4; t++)
                av[t] = *(const long*)(pa + t * 16 * BKB + kk);
#pragma unroll
            for (int t = 0; t < 4; t++)
                bv[t] = *(const long*)(pb + t * 16 * BKB + kk);
#pragma unroll
            for (int mi = 0; mi < 4; mi++)
#pragma unroll
                for (int ni = 0; ni < 4; ni++)
                    acc[mi][ni] = __builtin_amdgcn_mfma_f32_16x16x32_fp8_fp8(
                        av[mi], bv[ni], acc[mi][ni], 0, 0, 0);
        }
        __syncthreads();
    }

    // ---- epilogue: dequant + bias ----
    const float is = isp[0];
#pragma unroll
    for (int ni = 0; ni < 4; ni++) {
        const int cidx = n0 + wn * 64 + ni * 16 + lr;
        const float sc = is * wsc[cidx / ocPerChunk];
        const float bs = bias[cidx];
#pragma unroll
        for (int mi = 0; mi < 4; mi++) {
            const int rbase = m0 + wm * 64 + mi * 16 + (lane >> 4) * 4;
#pragma unroll
            for (int j = 0; j < 4; j++)
                out[(size_t)(rbase + j) * N + cidx] = acc[mi][ni][j] * sc + bs;
        }
    }
}

// ---------------------------------------------------------------------------
extern "C" void kernel_launch(void* const* d_in, const int* in_sizes, int n_in,
                              void* d_out, int out_size, void* d_ws, size_t ws_size,
                              hipStream_t stream) {
    const float* x        = (const float*)d_in[0];
    const float* w        = (const float*)d_in[1];
    const float* bias     = (const float*)d_in[2];
    const float* in_scale = (const float*)d_in[3];
    const float* w_scales = (const float*)d_in[4];
    float* out = (float*)d_out;

    const int N = in_sizes[2];               // 4096 (bias length = OUT)
    const int K = in_sizes[1] / N;           // 4096
    const int M = in_sizes[0] / K;           // 16384
    const int CHUNKS = in_sizes[4];          // 4
    const int ocPerChunk = N / CHUNKS;       // 1024

    uint8_t* xq = (uint8_t*)d_ws;            // M*K bytes
    uint8_t* wq = xq + (size_t)M * K;        // N*K bytes

    const int xn16 = (M * K) / 16 >= 0 ? (int)(((size_t)M * K) / 16) : 0;
    const int wn16 = (int)(((size_t)N * K) / 16);
    const int chunk16 = (N / CHUNKS) * K / 16;  // 16-elem groups per chunk

    quant_x_kernel<<<2048, 256, 0, stream>>>(x, in_scale, (uint4*)xq, xn16);
    quant_w_kernel<<<2048, 256, 0, stream>>>(w, w_scales, (uint4*)wq, wn16, chunk16);

    dim3 grid(N / BN, M / BM);  // (32, 128)
    gemm_fp8_kernel<<<grid, 256, 0, stream>>>(xq, wq, bias, in_scale, w_scales,
                                              out, M, N, K, ocPerChunk);
}

// Round 2
// 430.265 us; speedup vs baseline: 4.3673x; 4.3673x over previous
//
#include <hip/hip_runtime.h>
#include <stdint.h>

#define E4M3_MAX 448.0f

typedef float f32x4 __attribute__((ext_vector_type(4)));

// ---------------------------------------------------------------------------
// async global -> LDS, 16 bytes per lane (global_load_lds_dwordx4)
// LDS dest must be wave-uniform base + lane*16 (HW constraint) -> dest stays
// LINEAR; the T2 swizzle is applied by pre-swizzling the GLOBAL source column
// and swizzling the LDS READ offset with the same involution (rule #21).
// ---------------------------------------------------------------------------
__device__ __forceinline__ void gload_lds16(const void* g, void* l) {
    __builtin_amdgcn_global_load_lds(
        (__attribute__((address_space(1))) void*)(void*)g,
        (__attribute__((address_space(3))) void*)l,
        16, 0, 0);
}

// pack 4 floats -> 4 e4m3fn bytes (RNE + saturate; pre-clamp matches jnp.clip)
__device__ __forceinline__ uint32_t quant4(float a, float b, float c, float d) {
    a = fminf(fmaxf(a, -E4M3_MAX), E4M3_MAX);
    b = fminf(fmaxf(b, -E4M3_MAX), E4M3_MAX);
    c = fminf(fmaxf(c, -E4M3_MAX), E4M3_MAX);
    d = fminf(fmaxf(d, -E4M3_MAX), E4M3_MAX);
    int q = 0;
    q = __builtin_amdgcn_cvt_pk_fp8_f32(a, b, q, false);  // bytes 0,1
    q = __builtin_amdgcn_cvt_pk_fp8_f32(c, d, q, true);   // bytes 2,3
    return (uint32_t)q;
}

// ---------------------------------------------------------------------------
// quantize x: [M*K] f32 -> e4m3 bytes, scale = 1/in_scale (scalar)
// ---------------------------------------------------------------------------
__global__ void quant_x_kernel(const float* __restrict__ x,
                               const float* __restrict__ scale_p,
                               uint4* __restrict__ xq, int n16) {
    const float inv = 1.0f / scale_p[0];
    const int stride = gridDim.x * blockDim.x;
    for (int i = blockIdx.x * blockDim.x + threadIdx.x; i < n16; i += stride) {
        const float4* p = (const float4*)x + (size_t)i * 4;
        float4 v0 = p[0], v1 = p[1], v2 = p[2], v3 = p[3];
        uint4 q;
        q.x = quant4(v0.x * inv, v0.y * inv, v0.z * inv, v0.w * inv);
        q.y = quant4(v1.x * inv, v1.y * inv, v1.z * inv, v1.w * inv);
        q.z = quant4(v2.x * inv, v2.y * inv, v2.z * inv, v2.w * inv);
        q.w = quant4(v3.x * inv, v3.y * inv, v3.z * inv, v3.w * inv);
        xq[i] = q;
    }
}

// ---------------------------------------------------------------------------
// quantize w: [N*K] f32 -> e4m3 bytes, per-chunk scale w_scales[c]
// ---------------------------------------------------------------------------
__global__ void quant_w_kernel(const float* __restrict__ w,
                               const float* __restrict__ wsc,
                               uint4* __restrict__ wq, int n16, int chunk16) {
    const int stride = gridDim.x * blockDim.x;
    for (int i = blockIdx.x * blockDim.x + threadIdx.x; i < n16; i += stride) {
        const float inv = 1.0f / wsc[i / chunk16];
        const float4* p = (const float4*)w + (size_t)i * 4;
        float4 v0 = p[0], v1 = p[1], v2 = p[2], v3 = p[3];
        uint4 q;
        q.x = quant4(v0.x * inv, v0.y * inv, v0.z * inv, v0.w * inv);
        q.y = quant4(v1.x * inv, v1.y * inv, v1.z * inv, v1.w * inv);
        q.z = quant4(v2.x * inv, v2.y * inv, v2.z * inv, v2.w * inv);
        q.w = quant4(v3.x * inv, v3.y * inv, v3.z * inv, v3.w * inv);
        wq[i] = q;
    }
}

// ---------------------------------------------------------------------------
// fp8 GEMM, m97 structure + T2 swizzle: 128x128 tile, BKB=128 bytes,
// 4 waves (2x2), each wave 64x64 = 4x4 fragments, mfma_f32_16x16x32_fp8_fp8.
// LDS byte map: LDS[row][c] = global[row][c ^ ((row&7)<<4)].
// ---------------------------------------------------------------------------
#define BM 128
#define BN 128
#define BKB 128  // K-bytes per LDS tile

__global__ __launch_bounds__(256, 3) void gemm_fp8_kernel(
    const uint8_t* __restrict__ Aq, const uint8_t* __restrict__ Bq,
    const float* __restrict__ bias, const float* __restrict__ isp,
    const float* __restrict__ wsc, float* __restrict__ out,
    int M, int N, int K, int ocPerChunk) {
    __shared__ __align__(16) uint8_t As[BM * BKB];
    __shared__ __align__(16) uint8_t Bs[BN * BKB];

    const int tid  = threadIdx.x;
    const int lane = tid & 63;
    const int wid  = tid >> 6;
    const int wm   = wid >> 1;   // 0..1
    const int wn   = wid & 1;    // 0..1
    const int m0   = blockIdx.y * BM;
    const int n0   = blockIdx.x * BN;

    const int lr = lane & 15;          // fragment row (A) / col (B)
    const int lk = (lane >> 4) * 8;    // k byte offset within 32-wide k-step
    const int sw = (lr & 7) << 4;      // T2 swizzle for this thread's rows

    f32x4 acc[4][4] = {};

    const uint8_t* pa = As + (wm * 64 + lr) * BKB;
    const uint8_t* pb = Bs + (wn * 64 + lr) * BKB;

    // staging indices (precomputed, loop-invariant parts)
    // idx = i*256 + tid; row = idx>>3; cb = (idx&7)*16; swizzled col = cb^((row&7)<<4)
    int srow[4], scol[4];
#pragma unroll
    for (int i = 0; i < 4; i++) {
        int idx = i * 256 + tid;
        srow[i] = idx >> 3;
        scol[i] = ((idx & 7) * 16) ^ ((srow[i] & 7) << 4);
    }

    for (int kt = 0; kt < K; kt += BKB) {
        // ---- stage A,B tiles: linear LDS dest, swizzled global source ----
#pragma unroll
        for (int i = 0; i < 4; i++) {
            int idx = i * 256 + tid;
            gload_lds16(Aq + (size_t)(m0 + srow[i]) * K + kt + scol[i], As + idx * 16);
            gload_lds16(Bq + (size_t)(n0 + srow[i]) * K + kt + scol[i], Bs + idx * 16);
        }
        __syncthreads();

        // ---- 4 k-steps of 32, 16 MFMA each; swizzled ds_read_b64 ----
#pragma unroll
        for (int kk = 0; kk < BKB; kk += 32) {
            const int off = (kk + lk) ^ sw;   // swizzled byte offset in row
            long av[4], bv[4];
#pragma unroll
            for (int t = 0; t < 4; t++)
                av[t] = *(const long*)(pa + t * 16 * BKB + off);
#pragma unroll
            for (int t = 0; t < 4; t++)
                bv[t] = *(const long*)(pb + t * 16 * BKB + off);
#pragma unroll
            for (int mi = 0; mi < 4; mi++)
#pragma unroll
                for (int ni = 0; ni < 4; ni++)
                    acc[mi][ni] = __builtin_amdgcn_mfma_f32_16x16x32_fp8_fp8(
                        av[mi], bv[ni], acc[mi][ni], 0, 0, 0);
        }
        __syncthreads();
    }

    // ---- epilogue: dequant + bias ----
    const float is = isp[0];
#pragma unroll
    for (int ni = 0; ni < 4; ni++) {
        const int cidx = n0 + wn * 64 + ni * 16 + lr;
        const float sc = is * wsc[cidx / ocPerChunk];
        const float bs = bias[cidx];
#pragma unroll
        for (int mi = 0; mi < 4; mi++) {
            const int rbase = m0 + wm * 64 + mi * 16 + (lane >> 4) * 4;
#pragma unroll
            for (int j = 0; j < 4; j++)
                out[(size_t)(rbase + j) * N + cidx] = acc[mi][ni][j] * sc + bs;
        }
    }
}

// ---------------------------------------------------------------------------
extern "C" void kernel_launch(void* const* d_in, const int* in_sizes, int n_in,
                              void* d_out, int out_size, void* d_ws, size_t ws_size,
                              hipStream_t stream) {
    const float* x        = (const float*)d_in[0];
    const float* w        = (const float*)d_in[1];
    const float* bias     = (const float*)d_in[2];
    const float* in_scale = (const float*)d_in[3];
    const float* w_scales = (const float*)d_in[4];
    float* out = (float*)d_out;

    const int N = in_sizes[2];               // 4096 (bias length = OUT)
    const int K = in_sizes[1] / N;           // 4096
    const int M = in_sizes[0] / K;           // 16384
    const int CHUNKS = in_sizes[4];          // 4
    const int ocPerChunk = N / CHUNKS;       // 1024

    uint8_t* xq = (uint8_t*)d_ws;            // M*K bytes
    uint8_t* wq = xq + (size_t)M * K;        // N*K bytes

    const int xn16 = (int)(((size_t)M * K) / 16);
    const int wn16 = (int)(((size_t)N * K) / 16);
    const int chunk16 = (N / CHUNKS) * K / 16;  // 16-elem groups per chunk

    quant_x_kernel<<<2048, 256, 0, stream>>>(x, in_scale, (uint4*)xq, xn16);
    quant_w_kernel<<<2048, 256, 0, stream>>>(w, w_scales, (uint4*)wq, wn16, chunk16);

    dim3 grid(N / BN, M / BM);  // (32, 128)
    gemm_fp8_kernel<<<grid, 256, 0, stream>>>(xq, wq, bias, in_scale, w_scales,
                                              out, M, N, K, ocPerChunk);
}

// Round 3
// 398.884 us; speedup vs baseline: 4.7109x; 1.0787x over previous
//
#include <hip/hip_runtime.h>
#include <stdint.h>

#define E4M3_MAX 448.0f

typedef float f32x4 __attribute__((ext_vector_type(4)));
typedef int   i32x4 __attribute__((ext_vector_type(4)));
typedef int   i32x8 __attribute__((ext_vector_type(8)));

// ---------------------------------------------------------------------------
// async global -> LDS, 16 bytes per lane (global_load_lds_dwordx4)
// LDS dest stays LINEAR (HW constraint); T2 swizzle is applied by
// pre-swizzling the GLOBAL source column and swizzling the LDS READ offset
// with the same involution (rule #21).
// ---------------------------------------------------------------------------
__device__ __forceinline__ void gload_lds16(const void* g, void* l) {
    __builtin_amdgcn_global_load_lds(
        (__attribute__((address_space(1))) void*)(void*)g,
        (__attribute__((address_space(3))) void*)l,
        16, 0, 0);
}

// pack 4 floats -> 4 e4m3fn bytes (RNE + saturate; pre-clamp matches jnp.clip)
__device__ __forceinline__ uint32_t quant4(float a, float b, float c, float d) {
    a = fminf(fmaxf(a, -E4M3_MAX), E4M3_MAX);
    b = fminf(fmaxf(b, -E4M3_MAX), E4M3_MAX);
    c = fminf(fmaxf(c, -E4M3_MAX), E4M3_MAX);
    d = fminf(fmaxf(d, -E4M3_MAX), E4M3_MAX);
    int q = 0;
    q = __builtin_amdgcn_cvt_pk_fp8_f32(a, b, q, false);  // bytes 0,1
    q = __builtin_amdgcn_cvt_pk_fp8_f32(c, d, q, true);   // bytes 2,3
    return (uint32_t)q;
}

// ---------------------------------------------------------------------------
// quantize x: [M*K] f32 -> e4m3 bytes, scale = 1/in_scale (scalar)
// ---------------------------------------------------------------------------
__global__ void quant_x_kernel(const float* __restrict__ x,
                               const float* __restrict__ scale_p,
                               uint4* __restrict__ xq, int n16) {
    const float inv = 1.0f / scale_p[0];
    const int stride = gridDim.x * blockDim.x;
    for (int i = blockIdx.x * blockDim.x + threadIdx.x; i < n16; i += stride) {
        const float4* p = (const float4*)x + (size_t)i * 4;
        float4 v0 = p[0], v1 = p[1], v2 = p[2], v3 = p[3];
        uint4 q;
        q.x = quant4(v0.x * inv, v0.y * inv, v0.z * inv, v0.w * inv);
        q.y = quant4(v1.x * inv, v1.y * inv, v1.z * inv, v1.w * inv);
        q.z = quant4(v2.x * inv, v2.y * inv, v2.z * inv, v2.w * inv);
        q.w = quant4(v3.x * inv, v3.y * inv, v3.z * inv, v3.w * inv);
        xq[i] = q;
    }
}

// ---------------------------------------------------------------------------
// quantize w: [N*K] f32 -> e4m3 bytes, per-chunk scale w_scales[c]
// ---------------------------------------------------------------------------
__global__ void quant_w_kernel(const float* __restrict__ w,
                               const float* __restrict__ wsc,
                               uint4* __restrict__ wq, int n16, int chunk16) {
    const int stride = gridDim.x * blockDim.x;
    for (int i = blockIdx.x * blockDim.x + threadIdx.x; i < n16; i += stride) {
        const float inv = 1.0f / wsc[i / chunk16];
        const float4* p = (const float4*)w + (size_t)i * 4;
        float4 v0 = p[0], v1 = p[1], v2 = p[2], v3 = p[3];
        uint4 q;
        q.x = quant4(v0.x * inv, v0.y * inv, v0.z * inv, v0.w * inv);
        q.y = quant4(v1.x * inv, v1.y * inv, v1.z * inv, v1.w * inv);
        q.z = quant4(v2.x * inv, v2.y * inv, v2.z * inv, v2.w * inv);
        q.w = quant4(v3.x * inv, v3.y * inv, v3.z * inv, v3.w * inv);
        wq[i] = q;
    }
}

// ---------------------------------------------------------------------------
// fp8 GEMM, m97 structure + T2 swizzle + MX-scaled MFMA (unit scales):
// 128x128 tile, BKB=128 bytes = exactly one K=128 MFMA step.
// 4 waves (2x2), each wave 64x64 = 4x4 fragments of 16x16,
// mfma_scale_f32_16x16x128_f8f6f4 with scale = 0x7F (2^0) -> bit-identical
// to non-scaled e4m3 math at 2.27x the MFMA rate.
// LDS byte map: LDS[row][c] = global[row][c ^ ((row&7)<<4)].
// Fragment layout (K=128 fp8): lane l holds row l&15, k-bytes (l>>4)*32.
// ---------------------------------------------------------------------------
#define BM 128
#define BN 128
#define BKB 128  // K-bytes per LDS tile

__global__ __launch_bounds__(256, 3) void gemm_fp8_kernel(
    const uint8_t* __restrict__ Aq, const uint8_t* __restrict__ Bq,
    const float* __restrict__ bias, const float* __restrict__ isp,
    const float* __restrict__ wsc, float* __restrict__ out,
    int M, int N, int K, int ocPerChunk) {
    __shared__ __align__(16) uint8_t As[BM * BKB];
    __shared__ __align__(16) uint8_t Bs[BN * BKB];

    const int tid  = threadIdx.x;
    const int lane = tid & 63;
    const int wid  = tid >> 6;
    const int wm   = wid >> 1;   // 0..1
    const int wn   = wid & 1;    // 0..1
    const int m0   = blockIdx.y * BM;
    const int n0   = blockIdx.x * BN;

    const int lr  = lane & 15;          // fragment row (A) / col (B)
    const int sw  = (lr & 7) << 4;      // T2 swizzle for this thread's rows
    const int g32 = (lane >> 4) * 32;   // k-byte base within K=128 step
    const int off0 = g32 ^ sw;          // swizzled addr of k-bytes [g32, g32+16)
    const int off1 = (g32 + 16) ^ sw;   // swizzled addr of k-bytes [g32+16, g32+32)

    f32x4 acc[4][4] = {};

    const uint8_t* pa = As + (wm * 64 + lr) * BKB;
    const uint8_t* pb = Bs + (wn * 64 + lr) * BKB;

    // staging indices: idx = i*256 + tid; row = idx>>3; col = ((idx&7)*16) ^ swz(row)
    int srow[4], scol[4];
#pragma unroll
    for (int i = 0; i < 4; i++) {
        int idx = i * 256 + tid;
        srow[i] = idx >> 3;
        scol[i] = ((idx & 7) * 16) ^ ((srow[i] & 7) << 4);
    }

    for (int kt = 0; kt < K; kt += BKB) {
        // ---- stage A,B tiles: linear LDS dest, swizzled global source ----
#pragma unroll
        for (int i = 0; i < 4; i++) {
            int idx = i * 256 + tid;
            gload_lds16(Aq + (size_t)(m0 + srow[i]) * K + kt + scol[i], As + idx * 16);
            gload_lds16(Bq + (size_t)(n0 + srow[i]) * K + kt + scol[i], Bs + idx * 16);
        }
        __syncthreads();

        // ---- one K=128 step: 8 fragment loads (16 ds_read_b128), 16 MFMA ----
        i32x8 av[4], bv[4];
#pragma unroll
        for (int t = 0; t < 4; t++) {
            i32x4 lo = *(const i32x4*)(pa + t * 16 * BKB + off0);
            i32x4 hi = *(const i32x4*)(pa + t * 16 * BKB + off1);
            av[t] = __builtin_shufflevector(lo, hi, 0, 1, 2, 3, 4, 5, 6, 7);
        }
#pragma unroll
        for (int t = 0; t < 4; t++) {
            i32x4 lo = *(const i32x4*)(pb + t * 16 * BKB + off0);
            i32x4 hi = *(const i32x4*)(pb + t * 16 * BKB + off1);
            bv[t] = __builtin_shufflevector(lo, hi, 0, 1, 2, 3, 4, 5, 6, 7);
        }
#pragma unroll
        for (int mi = 0; mi < 4; mi++)
#pragma unroll
            for (int ni = 0; ni < 4; ni++)
                acc[mi][ni] = __builtin_amdgcn_mfma_scale_f32_16x16x128_f8f6f4(
                    av[mi], bv[ni], acc[mi][ni],
                    0 /*fp8 A*/, 0 /*fp8 B*/,
                    0, 0x7F7F7F7F,   // scale_a = 2^0
                    0, 0x7F7F7F7F);  // scale_b = 2^0
        __syncthreads();
    }

    // ---- epilogue: dequant + bias (16x16 C/D: col=lane&15, row=(lane>>4)*4+j) ----
    const float is = isp[0];
#pragma unroll
    for (int ni = 0; ni < 4; ni++) {
        const int cidx = n0 + wn * 64 + ni * 16 + lr;
        const float sc = is * wsc[cidx / ocPerChunk];
        const float bs = bias[cidx];
#pragma unroll
        for (int mi = 0; mi < 4; mi++) {
            const int rbase = m0 + wm * 64 + mi * 16 + (lane >> 4) * 4;
#pragma unroll
            for (int j = 0; j < 4; j++)
                out[(size_t)(rbase + j) * N + cidx] = acc[mi][ni][j] * sc + bs;
        }
    }
}

// ---------------------------------------------------------------------------
extern "C" void kernel_launch(void* const* d_in, const int* in_sizes, int n_in,
                              void* d_out, int out_size, void* d_ws, size_t ws_size,
                              hipStream_t stream) {
    const float* x        = (const float*)d_in[0];
    const float* w        = (const float*)d_in[1];
    const float* bias     = (const float*)d_in[2];
    const float* in_scale = (const float*)d_in[3];
    const float* w_scales = (const float*)d_in[4];
    float* out = (float*)d_out;

    const int N = in_sizes[2];               // 4096 (bias length = OUT)
    const int K = in_sizes[1] / N;           // 4096
    const int M = in_sizes[0] / K;           // 16384
    const int CHUNKS = in_sizes[4];          // 4
    const int ocPerChunk = N / CHUNKS;       // 1024

    uint8_t* xq = (uint8_t*)d_ws;            // M*K bytes
    uint8_t* wq = xq + (size_t)M * K;        // N*K bytes

    const int xn16 = (int)(((size_t)M * K) / 16);
    const int wn16 = (int)(((size_t)N * K) / 16);
    const int chunk16 = (N / CHUNKS) * K / 16;  // 16-elem groups per chunk

    quant_x_kernel<<<2048, 256, 0, stream>>>(x, in_scale, (uint4*)xq, xn16);
    quant_w_kernel<<<2048, 256, 0, stream>>>(w, w_scales, (uint4*)wq, wn16, chunk16);

    dim3 grid(N / BN, M / BM);  // (32, 128)
    gemm_fp8_kernel<<<grid, 256, 0, stream>>>(xq, wq, bias, in_scale, w_scales,
                                              out, M, N, K, ocPerChunk);
}